// Round 12
// baseline (326.535 us; speedup 1.0000x reference)
//
#include <hip/hip_runtime.h>
#include <math.h>

#define BZ 32
#define SRC_LEN 2048
#define DIM 1024
#define NSPAN 64

typedef float f4 __attribute__((ext_vector_type(4)));

// ---- kernel A: proj = tgt @ Wg^T ; 1-wave blocks, 2 rows/block --------------
// grid 512 blocks x 64 thr. Also zeroes the flash fan-in counters (block 0),
// which is safe: kA is a strictly-earlier dispatch than k_flash on the stream.
__global__ __launch_bounds__(64) void kA(const float* __restrict__ Wg,
                                         const float* __restrict__ tgt,
                                         float* __restrict__ proj,
                                         unsigned* __restrict__ counters) {
    const int lane = threadIdx.x;
    if (blockIdx.x == 0 && lane < BZ) counters[lane] = 0u;

    const int r0 = blockIdx.x * 2;
    const int r1 = r0 + 1;
    const float* W0 = &Wg[(size_t)r0 * DIM];
    const float* W1 = &Wg[(size_t)r1 * DIM];
    f4 w0[4], w1[4];
#pragma unroll
    for (int i = 0; i < 4; ++i) {
        w0[i] = *(const f4*)&W0[i * 256 + lane * 4];
        w1[i] = *(const f4*)&W1[i * 256 + lane * 4];
    }
    float acc0[BZ], acc1[BZ];
#pragma unroll
    for (int b = 0; b < BZ; ++b) { acc0[b] = 0.f; acc1[b] = 0.f; }
#pragma unroll
    for (int b = 0; b < BZ; ++b) {
#pragma unroll
        for (int i = 0; i < 4; ++i) {
            const f4 a = *(const f4*)&tgt[b * DIM + i * 256 + lane * 4];
            acc0[b] = fmaf(w0[i].x, a.x, acc0[b]);
            acc0[b] = fmaf(w0[i].y, a.y, acc0[b]);
            acc0[b] = fmaf(w0[i].z, a.z, acc0[b]);
            acc0[b] = fmaf(w0[i].w, a.w, acc0[b]);
            acc1[b] = fmaf(w1[i].x, a.x, acc1[b]);
            acc1[b] = fmaf(w1[i].y, a.y, acc1[b]);
            acc1[b] = fmaf(w1[i].z, a.z, acc1[b]);
            acc1[b] = fmaf(w1[i].w, a.w, acc1[b]);
        }
    }
#pragma unroll
    for (int b = 0; b < BZ; ++b) {
#pragma unroll
        for (int off = 32; off > 0; off >>= 1) {
            acc0[b] += __shfl_xor(acc0[b], off, 64);
            acc1[b] += __shfl_xor(acc1[b], off, 64);
        }
    }
    if (lane == 0) {
#pragma unroll
        for (int b = 0; b < BZ; ++b) {
            proj[b * DIM + r0] = acc0[b];
            proj[b * DIM + r1] = acc1[b];
        }
    }
}

// ---- kernel B: out = [c, tgt] @ Wo^T ; 1-wave blocks, 2 rows/block, K=2048 --
// grid 512 blocks x 64 thr.
__global__ __launch_bounds__(64) void kB(const float* __restrict__ Wo,
                                         const float* __restrict__ c_ws,
                                         const float* __restrict__ tgt,
                                         float* __restrict__ outp) {
    const int lane = threadIdx.x;
    const int d0 = blockIdx.x * 2;
    const int d1 = d0 + 1;
    const float* W0 = &Wo[(size_t)d0 * (2 * DIM)];
    const float* W1 = &Wo[(size_t)d1 * (2 * DIM)];
    f4 w0[8], w1[8];
#pragma unroll
    for (int i = 0; i < 8; ++i) {
        w0[i] = *(const f4*)&W0[i * 256 + lane * 4];
        w1[i] = *(const f4*)&W1[i * 256 + lane * 4];
    }
    float acc0[BZ], acc1[BZ];
#pragma unroll
    for (int b = 0; b < BZ; ++b) { acc0[b] = 0.f; acc1[b] = 0.f; }
#pragma unroll
    for (int b = 0; b < BZ; ++b) {
#pragma unroll
        for (int i = 0; i < 8; ++i) {   // i<4: c part, i>=4: tgt part
            const float* act = (i < 4) ? &c_ws[b * DIM + i * 256]
                                       : &tgt[b * DIM + (i - 4) * 256];
            const f4 a = *(const f4*)&act[lane * 4];
            acc0[b] = fmaf(w0[i].x, a.x, acc0[b]);
            acc0[b] = fmaf(w0[i].y, a.y, acc0[b]);
            acc0[b] = fmaf(w0[i].z, a.z, acc0[b]);
            acc0[b] = fmaf(w0[i].w, a.w, acc0[b]);
            acc1[b] = fmaf(w1[i].x, a.x, acc1[b]);
            acc1[b] = fmaf(w1[i].y, a.y, acc1[b]);
            acc1[b] = fmaf(w1[i].z, a.z, acc1[b]);
            acc1[b] = fmaf(w1[i].w, a.w, acc1[b]);
        }
    }
#pragma unroll
    for (int b = 0; b < BZ; ++b) {
#pragma unroll
        for (int off = 32; off > 0; off >>= 1) {
            acc0[b] += __shfl_xor(acc0[b], off, 64);
            acc1[b] += __shfl_xor(acc1[b], off, 64);
        }
    }
    if (lane == 0) {
#pragma unroll
        for (int b = 0; b < BZ; ++b) {
            outp[b * DIM + d0] = acc0[b];
            outp[b * DIM + d1] = acc1[b];
        }
    }
}

// ---- flash + fan-in merge tail ----------------------------------------------
// grid = 64 spans * 32 b = 2048 blocks x 256 thr. The 64th block to finish a
// batch (atomic ticket) merges that batch's partials and writes c_ws + align.
__global__ __launch_bounds__(256, 2) void k_flash(const float* __restrict__ src,
                                                  const float* __restrict__ proj,
                                                  const int* __restrict__ lens,
                                                  float* __restrict__ scores,
                                                  float* __restrict__ part_ml,
                                                  float* __restrict__ part_c,
                                                  unsigned* __restrict__ counters,
                                                  float* __restrict__ c_ws,
                                                  float* __restrict__ out_align) {
    __shared__ float s_c[4][1024];
    __shared__ float s_ml[4][2];
    __shared__ float se[NSPAN];
    __shared__ unsigned s_ticket;
    const int blk = blockIdx.x;
    const int b = blk & 31;
    const int g = blk >> 5;
    const int t = threadIdx.x, lane = t & 63, wave = t >> 6;
    const int len = lens[b];
    const int r0 = (g * len) >> 6;
    const int r1 = ((g + 1) * len) >> 6;   // union over g = [0, len)
    const int n  = r1 - r0;
    int nb = n - 8 * wave; nb = nb < 0 ? 0 : (nb > 8 ? 8 : nb);
    const float* sb = src + ((size_t)b * SRC_LEN + r0 + 8 * wave) * DIM;

    f4 pj[4];
#pragma unroll
    for (int q = 0; q < 4; ++q)
        pj[q] = *(const f4*)&proj[b * DIM + (q * 64 + lane) * 4];

    f4 v[8][4];
#pragma unroll
    for (int r = 0; r < 8; ++r) {
        if (r < nb) {
#pragma unroll
            for (int q = 0; q < 4; ++q)
                v[r][q] = *(const f4*)&sb[r * DIM + (q * 64 + lane) * 4];
        }
    }
    float sc[8];
#pragma unroll
    for (int r = 0; r < 8; ++r) {
        if (r < nb) {
            const f4 d = v[r][0] * pj[0] + v[r][1] * pj[1] +
                         v[r][2] * pj[2] + v[r][3] * pj[3];
            sc[r] = d.x + d.y + d.z + d.w;
        } else {
            sc[r] = -INFINITY;
        }
    }
#pragma unroll
    for (int off = 32; off > 0; off >>= 1) {
#pragma unroll
        for (int r = 0; r < 8; ++r) sc[r] += __shfl_xor(sc[r], off, 64);
    }
    if (lane == 0) {
#pragma unroll
        for (int r = 0; r < 8; ++r)
            if (r < nb) scores[b * SRC_LEN + r0 + 8 * wave + r] = sc[r];
    }

    float m = -INFINITY, l = 0.f;
    f4 c[4] = {{0.f,0.f,0.f,0.f},{0.f,0.f,0.f,0.f},{0.f,0.f,0.f,0.f},{0.f,0.f,0.f,0.f}};
    if (nb > 0) {
#pragma unroll
        for (int r = 0; r < 8; ++r) m = fmaxf(m, sc[r]);
        float w[8];
#pragma unroll
        for (int r = 0; r < 8; ++r) { w[r] = __expf(sc[r] - m); l += w[r]; }
#pragma unroll
        for (int r = 0; r < 8; ++r) {
            if (r < nb) {
#pragma unroll
                for (int q = 0; q < 4; ++q) c[q] += w[r] * v[r][q];
            }
        }
    }

#pragma unroll
    for (int q = 0; q < 4; ++q)
        *(f4*)&s_c[wave][(q * 64 + lane) * 4] = c[q];
    if (lane == 0) { s_ml[wave][0] = m; s_ml[wave][1] = l; }
    __syncthreads();

    float M4 = fmaxf(fmaxf(s_ml[0][0], s_ml[1][0]), fmaxf(s_ml[2][0], s_ml[3][0]));
    float L4 = 0.f;
    f4 acc = {0.f, 0.f, 0.f, 0.f};
#pragma unroll
    for (int wv = 0; wv < 4; ++wv) {
        const float mw = s_ml[wv][0];
        const float e = (mw == -INFINITY) ? 0.f : __expf(mw - M4);
        L4 += e * s_ml[wv][1];
        const f4 cv = *(const f4*)&s_c[wv][t * 4];
        acc += e * cv;
    }
    if (t == 0) { part_ml[2 * blk] = M4; part_ml[2 * blk + 1] = L4; }
    *(f4*)&part_c[(size_t)blk * DIM + t * 4] = acc;   // ALWAYS (dead -> zeros)

    // ---- fan-in: last block of batch b merges ------------------------------
    __threadfence();                       // release this block's stores
    __syncthreads();                       // all threads' stores fenced
    if (t == 0) s_ticket = atomicAdd(&counters[b], 1u);
    __syncthreads();
    if (s_ticket != NSPAN - 1) return;

    __threadfence();                       // acquire other blocks' stores

    // M, L over 64 spans: span id = lane (each wave redundantly identical)
    const float m_t = part_ml[2 * (lane * BZ + b)];
    const float l_t = part_ml[2 * (lane * BZ + b) + 1];
    float M = m_t;
#pragma unroll
    for (int off = 32; off > 0; off >>= 1) M = fmaxf(M, __shfl_xor(M, off, 64));
    const float e_t = (m_t > -INFINITY) ? __expf(m_t - M) : 0.f;
    float L = e_t * l_t;
#pragma unroll
    for (int off = 32; off > 0; off >>= 1) L += __shfl_xor(L, off, 64);
    const float invL = 1.f / L;
    if (wave == 0) se[lane] = e_t;
    __syncthreads();

    // c[b][col], col = t*4..t*4+3 ; sum over 64 spans, 8 loads in flight
    f4 cacc = {0.f, 0.f, 0.f, 0.f};
    for (int i0 = 0; i0 < NSPAN; i0 += 8) {
        f4 vv[8];
#pragma unroll
        for (int u = 0; u < 8; ++u)
            vv[u] = *(const f4*)&part_c[(size_t)((i0 + u) * BZ + b) * DIM + t * 4];
#pragma unroll
        for (int u = 0; u < 8; ++u) cacc += se[i0 + u] * vv[u];
    }
    *(f4*)&c_ws[b * DIM + t * 4] = cacc * invL;

    // align row for batch b
#pragma unroll
    for (int u = 0; u < 8; ++u) {
        const int s = u * 256 + t;
        float a = 0.f;
        if (s < len) a = __expf(scores[b * SRC_LEN + s] - M) * invL;
        out_align[b * SRC_LEN + s] = a;
    }
}

extern "C" void kernel_launch(void* const* d_in, const int* in_sizes, int n_in,
                              void* d_out, int out_size, void* d_ws, size_t ws_size,
                              hipStream_t stream) {
    const float* src = (const float*)d_in[0];   // (32, 2048, 1024)
    const float* tgt = (const float*)d_in[1];   // (32, 1, 1024)
    const float* Wg  = (const float*)d_in[2];   // (1024, 1024)
    const float* Wo  = (const float*)d_in[3];   // (1024, 2048)
    const int*   len = (const int*)d_in[4];     // (32,)
    float* out = (float*)d_out;                 // attn_h [0,32768) ++ align

    float* ws = (float*)d_ws;
    float* proj    = ws;                               // 32*1024
    float* scores  = proj + BZ * DIM;                  // 32*2048
    float* part_ml = scores + BZ * SRC_LEN;            // 2048*2
    float* part_c  = part_ml + BZ * NSPAN * 2;         // 2048*1024 (8 MB)
    float* c_ws    = part_c + (size_t)BZ * NSPAN * DIM;    // 32*1024
    unsigned* counters = (unsigned*)(c_ws + BZ * DIM); // 32 (re-zeroed by kA)

    kA     <<<512,         64,  0, stream>>>(Wg, tgt, proj, counters);
    k_flash<<<BZ * NSPAN,  256, 0, stream>>>(src, proj, len, scores, part_ml,
                                             part_c, counters, c_ws,
                                             out + BZ * DIM);
    kB     <<<512,         64,  0, stream>>>(Wo, c_ws, tgt, out);
}

// Round 13
// 59.822 us; speedup vs baseline: 5.4585x; 5.4585x over previous
//
#include <hip/hip_runtime.h>
#include <math.h>

#define BZ 32
#define SRC_LEN 2048
#define DIM 1024
#define NSPAN 64

typedef float f4 __attribute__((ext_vector_type(4)));

// ---- kernel A: 1-wave blocks, 2 W-rows/block, activations direct -----------
// virtual rows 0..1023   -> proj[b][r]       = Wg[r] . tgt[b]
// virtual rows 1024..2047-> tpart[b][r-1024] = Wo[r-1024][1024:] . tgt[b]
// grid 1024 blocks x 64 thr (4 blocks/CU).
__global__ __launch_bounds__(64) void kA(const float* __restrict__ Wg,
                                         const float* __restrict__ Wo,
                                         const float* __restrict__ tgt,
                                         float* __restrict__ proj,
                                         float* __restrict__ tpart) {
    const int lane = threadIdx.x;
    const int r0 = blockIdx.x * 2;
    const int r1 = r0 + 1;
    const float* W0 = (r0 < DIM) ? &Wg[(size_t)r0 * DIM]
                                 : &Wo[(size_t)(r0 - DIM) * (2 * DIM) + DIM];
    const float* W1 = (r1 < DIM) ? &Wg[(size_t)r1 * DIM]
                                 : &Wo[(size_t)(r1 - DIM) * (2 * DIM) + DIM];
    f4 w0[4], w1[4];
#pragma unroll
    for (int i = 0; i < 4; ++i) {
        w0[i] = *(const f4*)&W0[i * 256 + lane * 4];
        w1[i] = *(const f4*)&W1[i * 256 + lane * 4];
    }
    float acc0[BZ], acc1[BZ];
#pragma unroll
    for (int b = 0; b < BZ; ++b) { acc0[b] = 0.f; acc1[b] = 0.f; }
#pragma unroll
    for (int b = 0; b < BZ; ++b) {
#pragma unroll
        for (int i = 0; i < 4; ++i) {
            const f4 a = *(const f4*)&tgt[b * DIM + i * 256 + lane * 4];
            acc0[b] = fmaf(w0[i].x, a.x, acc0[b]);
            acc0[b] = fmaf(w0[i].y, a.y, acc0[b]);
            acc0[b] = fmaf(w0[i].z, a.z, acc0[b]);
            acc0[b] = fmaf(w0[i].w, a.w, acc0[b]);
            acc1[b] = fmaf(w1[i].x, a.x, acc1[b]);
            acc1[b] = fmaf(w1[i].y, a.y, acc1[b]);
            acc1[b] = fmaf(w1[i].z, a.z, acc1[b]);
            acc1[b] = fmaf(w1[i].w, a.w, acc1[b]);
        }
    }
#pragma unroll
    for (int b = 0; b < BZ; ++b) {
#pragma unroll
        for (int off = 32; off > 0; off >>= 1) {
            acc0[b] += __shfl_xor(acc0[b], off, 64);
            acc1[b] += __shfl_xor(acc1[b], off, 64);
        }
    }
    if (lane == 0) {
        if (r0 < DIM) {
#pragma unroll
            for (int b = 0; b < BZ; ++b) {
                proj[b * DIM + r0] = acc0[b];
                proj[b * DIM + r1] = acc1[b];
            }
        } else {
#pragma unroll
            for (int b = 0; b < BZ; ++b) {
                tpart[b * DIM + (r0 - DIM)] = acc0[b];
                tpart[b * DIM + (r1 - DIM)] = acc1[b];
            }
        }
    }
}

// ---- kernel B: out = c@Wo_left^T + tpart; 1-wave blocks, 2 rows/block ------
// grid 512 blocks x 64 thr (2 blocks/CU).
__global__ __launch_bounds__(64) void kB(const float* __restrict__ Wo,
                                         const float* __restrict__ c_ws,
                                         const float* __restrict__ tpart,
                                         float* __restrict__ outp) {
    const int lane = threadIdx.x;
    const int d0 = blockIdx.x * 2;
    const int d1 = d0 + 1;
    const float* W0 = &Wo[(size_t)d0 * (2 * DIM)];   // left half (cols 0..1023)
    const float* W1 = &Wo[(size_t)d1 * (2 * DIM)];
    f4 w0[4], w1[4];
#pragma unroll
    for (int i = 0; i < 4; ++i) {
        w0[i] = *(const f4*)&W0[i * 256 + lane * 4];
        w1[i] = *(const f4*)&W1[i * 256 + lane * 4];
    }
    float acc0[BZ], acc1[BZ];
#pragma unroll
    for (int b = 0; b < BZ; ++b) { acc0[b] = 0.f; acc1[b] = 0.f; }
#pragma unroll
    for (int b = 0; b < BZ; ++b) {
#pragma unroll
        for (int i = 0; i < 4; ++i) {
            const f4 a = *(const f4*)&c_ws[b * DIM + i * 256 + lane * 4];
            acc0[b] = fmaf(w0[i].x, a.x, acc0[b]);
            acc0[b] = fmaf(w0[i].y, a.y, acc0[b]);
            acc0[b] = fmaf(w0[i].z, a.z, acc0[b]);
            acc0[b] = fmaf(w0[i].w, a.w, acc0[b]);
            acc1[b] = fmaf(w1[i].x, a.x, acc1[b]);
            acc1[b] = fmaf(w1[i].y, a.y, acc1[b]);
            acc1[b] = fmaf(w1[i].z, a.z, acc1[b]);
            acc1[b] = fmaf(w1[i].w, a.w, acc1[b]);
        }
    }
#pragma unroll
    for (int b = 0; b < BZ; ++b) {
#pragma unroll
        for (int off = 32; off > 0; off >>= 1) {
            acc0[b] += __shfl_xor(acc0[b], off, 64);
            acc1[b] += __shfl_xor(acc1[b], off, 64);
        }
    }
    if (lane == 0) {
#pragma unroll
        for (int b = 0; b < BZ; ++b) {
            outp[b * DIM + d0] = acc0[b] + tpart[b * DIM + d0];
            outp[b * DIM + d1] = acc1[b] + tpart[b * DIM + d1];
        }
    }
}

// ---- flash: proven 21.2 us streaming-floor version -------------------------
__global__ __launch_bounds__(256, 2) void k_flash(const float* __restrict__ src,
                                                  const float* __restrict__ proj,
                                                  const int* __restrict__ lens,
                                                  float* __restrict__ scores,
                                                  float* __restrict__ part_ml,
                                                  float* __restrict__ part_c) {
    __shared__ float s_c[4][1024];
    __shared__ float s_ml[4][2];
    const int blk = blockIdx.x;
    const int b = blk & 31;
    const int g = blk >> 5;
    const int t = threadIdx.x, lane = t & 63, wave = t >> 6;
    const int len = lens[b];
    const int r0 = (g * len) >> 6;
    const int r1 = ((g + 1) * len) >> 6;   // union over g = [0, len)
    const int n  = r1 - r0;
    int nb = n - 8 * wave; nb = nb < 0 ? 0 : (nb > 8 ? 8 : nb);
    const float* sb = src + ((size_t)b * SRC_LEN + r0 + 8 * wave) * DIM;

    f4 pj[4];
#pragma unroll
    for (int q = 0; q < 4; ++q)
        pj[q] = *(const f4*)&proj[b * DIM + (q * 64 + lane) * 4];

    f4 v[8][4];
#pragma unroll
    for (int r = 0; r < 8; ++r) {
        if (r < nb) {
#pragma unroll
            for (int q = 0; q < 4; ++q)
                v[r][q] = *(const f4*)&sb[r * DIM + (q * 64 + lane) * 4];
        }
    }
    float sc[8];
#pragma unroll
    for (int r = 0; r < 8; ++r) {
        if (r < nb) {
            const f4 d = v[r][0] * pj[0] + v[r][1] * pj[1] +
                         v[r][2] * pj[2] + v[r][3] * pj[3];
            sc[r] = d.x + d.y + d.z + d.w;
        } else {
            sc[r] = -INFINITY;
        }
    }
#pragma unroll
    for (int off = 32; off > 0; off >>= 1) {
#pragma unroll
        for (int r = 0; r < 8; ++r) sc[r] += __shfl_xor(sc[r], off, 64);
    }
    if (lane == 0) {
#pragma unroll
        for (int r = 0; r < 8; ++r)
            if (r < nb) scores[b * SRC_LEN + r0 + 8 * wave + r] = sc[r];
    }

    float m = -INFINITY, l = 0.f;
    f4 c[4] = {{0.f,0.f,0.f,0.f},{0.f,0.f,0.f,0.f},{0.f,0.f,0.f,0.f},{0.f,0.f,0.f,0.f}};
    if (nb > 0) {
#pragma unroll
        for (int r = 0; r < 8; ++r) m = fmaxf(m, sc[r]);
        float w[8];
#pragma unroll
        for (int r = 0; r < 8; ++r) { w[r] = __expf(sc[r] - m); l += w[r]; }
#pragma unroll
        for (int r = 0; r < 8; ++r) {
            if (r < nb) {
#pragma unroll
                for (int q = 0; q < 4; ++q) c[q] += w[r] * v[r][q];
            }
        }
    }

#pragma unroll
    for (int q = 0; q < 4; ++q)
        *(f4*)&s_c[wave][(q * 64 + lane) * 4] = c[q];
    if (lane == 0) { s_ml[wave][0] = m; s_ml[wave][1] = l; }
    __syncthreads();

    float M = fmaxf(fmaxf(s_ml[0][0], s_ml[1][0]), fmaxf(s_ml[2][0], s_ml[3][0]));
    float L = 0.f;
    f4 acc = {0.f, 0.f, 0.f, 0.f};
#pragma unroll
    for (int wv = 0; wv < 4; ++wv) {
        const float mw = s_ml[wv][0];
        const float e = (mw == -INFINITY) ? 0.f : __expf(mw - M);
        L += e * s_ml[wv][1];
        const f4 cv = *(const f4*)&s_c[wv][t * 4];
        acc += e * cv;
    }
    if (t == 0) { part_ml[2 * blk] = M; part_ml[2 * blk + 1] = L; }
    *(f4*)&part_c[(size_t)blk * DIM + t * 4] = acc;   // ALWAYS (dead -> zeros)
}

// ---- merge: 512 one-wave blocks (b, 16 col-slices), in-register M/L --------
__global__ __launch_bounds__(64) void k_merge(const float* __restrict__ part_ml,
                                              const float* __restrict__ part_c,
                                              const float* __restrict__ scores,
                                              const int* __restrict__ lens,
                                              float* __restrict__ c_ws,
                                              float* __restrict__ out_align) {
    __shared__ float se[NSPAN];
    const int b = blockIdx.x & 31;
    const int slice = blockIdx.x >> 5;         // 0..15
    const int lane = threadIdx.x;              // 0..63 == span id

    const float m_t = part_ml[2 * (lane * BZ + b)];
    const float l_t = part_ml[2 * (lane * BZ + b) + 1];
    float M = m_t;
#pragma unroll
    for (int off = 32; off > 0; off >>= 1) M = fmaxf(M, __shfl_xor(M, off, 64));
    const float e_t = (m_t > -INFINITY) ? __expf(m_t - M) : 0.f;
    float L = e_t * l_t;
#pragma unroll
    for (int off = 32; off > 0; off >>= 1) L += __shfl_xor(L, off, 64);
    const float invL = 1.f / L;

    se[lane] = e_t;
    __syncthreads();

    const int col = slice * 64 + lane;
    float acc = 0.f;
    for (int i0 = 0; i0 < NSPAN; i0 += 8) {
        float vv[8];
#pragma unroll
        for (int u = 0; u < 8; ++u)          // 8 independent loads in flight
            vv[u] = part_c[(size_t)((i0 + u) * BZ + b) * DIM + col];
#pragma unroll
        for (int u = 0; u < 8; ++u) acc += se[i0 + u] * vv[u];
    }
    c_ws[b * DIM + col] = acc * invL;

    const int len = lens[b];
#pragma unroll
    for (int u = 0; u < 2; ++u) {
        const int s = slice * 128 + u * 64 + lane;
        float a = 0.f;
        if (s < len) a = __expf(scores[b * SRC_LEN + s] - M) * invL;
        out_align[b * SRC_LEN + s] = a;
    }
}

extern "C" void kernel_launch(void* const* d_in, const int* in_sizes, int n_in,
                              void* d_out, int out_size, void* d_ws, size_t ws_size,
                              hipStream_t stream) {
    const float* src = (const float*)d_in[0];   // (32, 2048, 1024)
    const float* tgt = (const float*)d_in[1];   // (32, 1, 1024)
    const float* Wg  = (const float*)d_in[2];   // (1024, 1024)
    const float* Wo  = (const float*)d_in[3];   // (1024, 2048)
    const int*   len = (const int*)d_in[4];     // (32,)
    float* out = (float*)d_out;                 // attn_h [0,32768) ++ align

    float* ws = (float*)d_ws;
    float* proj    = ws;                               // 32*1024
    float* scores  = proj + BZ * DIM;                  // 32*2048
    float* part_ml = scores + BZ * SRC_LEN;            // 2048*2
    float* part_c  = part_ml + BZ * NSPAN * 2;         // 2048*1024 (8 MB)
    float* c_ws    = part_c + (size_t)BZ * NSPAN * DIM;
    float* tpart   = c_ws + BZ * DIM;

    kA     <<<1024,        64,  0, stream>>>(Wg, Wo, tgt, proj, tpart);
    k_flash<<<BZ * NSPAN,  256, 0, stream>>>(src, proj, len, scores, part_ml, part_c);
    k_merge<<<512,         64,  0, stream>>>(part_ml, part_c, scores, len, c_ws, out + BZ * DIM);
    kB     <<<512,         64,  0, stream>>>(Wo, c_ws, tpart, out);
}